// Round 9
// baseline (152.060 us; speedup 1.0000x reference)
//
#include <hip/hip_runtime.h>

#define NN 32
#define MAX_ITERS 10
#define TPB 256

// Projection math validated R1-R8 (bit-exact algebraic form of reference):
//  forward = 31-step prefix-min; backward: q[u] = med3(p[u], max_child, q_fwd[u-1]).
__device__ __forceinline__ void project(float p[NN], float q[NN]) {
    #pragma unroll 1
    for (int it = 0; it < MAX_ITERS; ++it) {
        #pragma unroll
        for (int u = 0; u < NN - 1; ++u)
            q[u + 1] = fminf(q[u + 1], q[u]);
        #pragma unroll
        for (int u = NN - 1; u >= 0; --u) {
            float maxc;
            if (u == NN - 1)      maxc = 0.0f;
            else if (u == NN - 2) maxc = q[NN - 1];
            else                  maxc = fmaxf(q[u + 1], q[u + 2]);
            float minp = (u == 0) ? 1.0f : q[u - 1];
            q[u] = __builtin_amdgcn_fmed3f(p[u], maxc, minp);
        }
    }
}

// ---- pass 1: pure elementwise sigmoid stream (x -> out), 134 MB traffic.
// Textbook grid-stride float4 pattern; calibrates achievable BW at this shape.
__global__ __launch_bounds__(TPB) void k_sigmoid(
    const float4* __restrict__ x, float4* __restrict__ out, int n4)
{
    int stride = gridDim.x * blockDim.x;
    for (int i = blockIdx.x * blockDim.x + threadIdx.x; i < n4; i += stride) {
        float4 v = x[i];
        v.x = __builtin_amdgcn_rcpf(1.0f + __expf(-v.x));
        v.y = __builtin_amdgcn_rcpf(1.0f + __expf(-v.y));
        v.z = __builtin_amdgcn_rcpf(1.0f + __expf(-v.z));
        v.w = __builtin_amdgcn_rcpf(1.0f + __expf(-v.w));
        out[i] = v;
    }
}

// ---- pass 2: in-place projection on d_out (reads its own row, writes back).
// Reads are L3-warm (written 20us ago); writes stream 67 MB to HBM.
__global__ __launch_bounds__(TPB) void k_project(float* __restrict__ out, int brows)
{
    int row = blockIdx.x * blockDim.x + threadIdx.x;
    if (row >= brows) return;
    float4* r = reinterpret_cast<float4*>(out) + (size_t)row * 8;
    float p[NN], q[NN];
    #pragma unroll
    for (int k = 0; k < 8; ++k) {
        float4 v = r[k];
        p[4*k+0] = v.x; p[4*k+1] = v.y; p[4*k+2] = v.z; p[4*k+3] = v.w;
    }
    #pragma unroll
    for (int i = 0; i < NN; ++i) q[i] = p[i];
    project(p, q);
    #pragma unroll
    for (int k = 0; k < 8; ++k)
        r[k] = make_float4(q[4*k+0], q[4*k+1], q[4*k+2], q[4*k+3]);
}

// ---- probe: 5x chained projection, 16 B in / 16 B out per thread.
// q[0] transitively depends on every p/q via the backward chain (DCE-live);
// p perturbed between reps so reps can't be folded. dur/5 = isolated compute.
__global__ __launch_bounds__(TPB) void probe_compute5(
    const float* __restrict__ x, float4* __restrict__ ws, int brows)
{
    int tid = blockIdx.x * blockDim.x + threadIdx.x;
    if (tid >= brows) return;
    float4 v = reinterpret_cast<const float4*>(x)[tid];
    float p[NN], q[NN];
    #pragma unroll
    for (int i = 0; i < NN; ++i) {
        float base = (i & 2) ? ((i & 1) ? v.w : v.z) : ((i & 1) ? v.y : v.x);
        p[i] = base * 0.11f + (float)i * 0.01f;
        q[i] = p[i];
    }
    #pragma unroll 1
    for (int rep = 0; rep < 5; ++rep) {
        project(p, q);
        #pragma unroll
        for (int i = 0; i < NN; ++i)
            p[i] = fmaxf(p[i] * 0.99f, q[i]);   // keep reps distinct & live
    }
    ws[tid] = make_float4(q[0], q[7], q[15], q[31]);
}

extern "C" void kernel_launch(void* const* d_in, const int* in_sizes, int n_in,
                              void* d_out, int out_size, void* d_ws, size_t ws_size,
                              hipStream_t stream)
{
    const float* x = (const float*)d_in[0];
    float* out = (float*)d_out;

    int total = in_sizes[0];      // B * N
    int brows = total / NN;       // B rows
    int n4 = total / 4;

    int blocks = (brows + TPB - 1) / TPB;   // 2048

    // correct output = pass1 + pass2 (bit-identical math to fused version)
    k_sigmoid<<<blocks, TPB, 0, stream>>>(
        (const float4*)x, (float4*)out, n4);
    k_project<<<blocks, TPB, 0, stream>>>(out, brows);

    // compute isolation probe (needs only brows*16 bytes of scratch)
    if (ws_size >= (size_t)brows * sizeof(float4))
        probe_compute5<<<blocks, TPB, 0, stream>>>(x, (float4*)d_ws, brows);
}

// Round 10
// 35.130 us; speedup vs baseline: 4.3285x; 4.3285x over previous
//
#include <hip/hip_runtime.h>

#define NN 32
#define MAX_ITERS 10
#define TPB 256

// DAG projection, graph compile-time constant (children u+1,u+2; parents u-1,u-2).
//
// R9 probe: compute is VALU-ISSUE-bound (~20us/projection, VALUBusy 89%,
// 1.5% HBM). So cut ops at the math level. Exact structural theorems:
//  T1: after iteration 1's backward pass q is non-increasing
//      (q'[u] = med3(p,maxc,f[u-1]) >= maxc >= q'[u+1]), so every later
//      forward prefix-min pass is the IDENTITY -> deleted.
//  T2: within any backward pass q'[u+1] >= q'[u+2] (induction: q'[u+1] =
//      med3(p, lo=q'[u+2], hi=f/q_old[u]) with lo<=hi), so
//      max_child = max(q'[u+1],q'[u+2]) = q'[u+1] exactly -> fmaxf deleted.
//  Backward pass = in-place descending med3 chain:
//      q[u] = med3(p[u], q[u+1](new), q[u-1](old))
//      u=31: maxc=0, minp=q[30] -> fminf(p[31], q[30])   (p>0)
//      u=0 : minp=1             -> fmaxf(p[0],  q[1])    (all values <1)
//  All identities bit-exact: fmin/fmax/med3 exact ops, values in (0,1), no NaN.
// Per-row math: 950 -> ~350 ops (iter1: 31 fmin + 32 med3; iters 2-10: 32).
// Iteration loop FULLY unrolled: straight-line SSA lets the allocator keep
// p+q in architectural VGPRs (rolled loop banked them in AGPRs: VGPR_Count=36
// with 64 floats live -> accvgpr moves ~3x'd the issue count, R9 probe).
__global__ __launch_bounds__(TPB) void dag_constraint_kernel(
    const float* __restrict__ x, float* __restrict__ out, int brows)
{
    const int row = blockIdx.x * blockDim.x + threadIdx.x;
    if (row >= brows) return;

    const float4* __restrict__ xr =
        reinterpret_cast<const float4*>(x) + (size_t)row * (NN / 4);

    float p[NN], q[NN];
    #pragma unroll
    for (int k = 0; k < NN / 4; ++k) {
        float4 v = xr[k];
        p[4*k+0] = v.x; p[4*k+1] = v.y; p[4*k+2] = v.z; p[4*k+3] = v.w;
    }

    // sigmoid via v_exp + v_rcp (1 ulp; error << 0.0198 threshold)
    #pragma unroll
    for (int i = 0; i < NN; ++i) {
        p[i] = __builtin_amdgcn_rcpf(1.0f + __expf(-p[i]));
        q[i] = p[i];
    }

    #pragma unroll
    for (int it = 0; it < MAX_ITERS; ++it) {
        if (it == 0) {
            // forward prefix-min (identity for it>=1 by T1)
            #pragma unroll
            for (int u = 0; u < NN - 1; ++u)
                q[u + 1] = fminf(q[u + 1], q[u]);
        }
        // backward: in-place descending med3 chain (T2)
        q[NN - 1] = fminf(p[NN - 1], q[NN - 2]);
        #pragma unroll
        for (int u = NN - 2; u >= 1; --u)
            q[u] = __builtin_amdgcn_fmed3f(p[u], q[u + 1], q[u - 1]);
        q[0] = fmaxf(p[0], q[1]);
    }

    float4* __restrict__ outr =
        reinterpret_cast<float4*>(out) + (size_t)row * (NN / 4);
    #pragma unroll
    for (int k = 0; k < NN / 4; ++k)
        outr[k] = make_float4(q[4*k+0], q[4*k+1], q[4*k+2], q[4*k+3]);
}

extern "C" void kernel_launch(void* const* d_in, const int* in_sizes, int n_in,
                              void* d_out, int out_size, void* d_ws, size_t ws_size,
                              hipStream_t stream)
{
    const float* x = (const float*)d_in[0];
    float* out = (float*)d_out;

    int total = in_sizes[0];      // B * N
    int brows = total / NN;       // B rows

    int blocks = (brows + TPB - 1) / TPB;   // 2048
    dag_constraint_kernel<<<blocks, TPB, 0, stream>>>(x, out, brows);
}